// Round 1
// baseline (40.537 us; speedup 1.0000x reference)
//
#include <hip/hip_runtime.h>

// Simple1DSSM: y = causal conv of x (64 x 8192) with SSM kernel K[m] = C diag(r^m) Bb.
// Implemented as a chunk-parallel diagonal-state scan (exact, no truncation):
//   T=64 chunk size, NC=128 chunks, D=64 states.
//   K1: hloc[b][c][d] = sum_j r_d^{T-1-j} Bb_d x[b,cT+j]   (stored in d_out)
//       + one extra block builds tables Mt[d][i]=C_d r_d^{i+1}, Kp (padded K[m]) in d_ws
//   K2: in-place scan over chunks: hin[c] = r^T hin[c-1] + hloc[c-1]
//   K3: y[b,cT+i] = sum_d Mt[d][i] hin[b][c][d] + sum_{j<=i} K[i-j] x[b,cT+j]

#define SEQ_L 8192
#define TCH   64
#define NCH   128   // SEQ_L / TCH
#define NB    64
#define DS    64

__global__ __launch_bounds__(256) void ssm_k1(const float* __restrict__ x,
                                              const float* __restrict__ A,
                                              const float* __restrict__ B,
                                              const float* __restrict__ C,
                                              const float* __restrict__ logd,
                                              float* __restrict__ out,
                                              float* __restrict__ ws)
{
    const float delta = expf(logd[0]);
    if (blockIdx.x == (NB * NCH) / 4) {
        // table block: 64 threads build Mt (4096 floats) and padded K (127 floats)
        if (threadIdx.x < 64) {
            const int i = threadIdx.x;
            float s = 0.f;
            for (int d = 0; d < DS; ++d) {
                const float Ad  = A[d];
                const float dAd = delta * Ad;
                const float rd  = expf(dAd);
                const float Bbd = (rd - 1.f) / Ad * B[d];
                const float wd  = C[d] * Bbd;
                const float p   = expf((float)i * dAd);   // r_d^i
                s = fmaf(wd, p, s);                       // K[i]
                ws[d * 64 + i] = C[d] * p * rd;           // Mt[d][i] = C_d r_d^{i+1}
            }
            ws[4096 + 63 + i] = s;                        // Kp[63+m] = K[m]
            if (i < 63) ws[4096 + i] = 0.f;               // Kp[m<0] = 0
        }
        return;
    }
    const int lane = threadIdx.x & 63;
    const int unit = blockIdx.x * 4 + (threadIdx.x >> 6);  // (b,c) pair
    const int b = unit >> 7;
    const int c = unit & (NCH - 1);
    const float Ad = A[lane];
    const float r  = expf(delta * Ad);
    const float Bb = (r - 1.f) / Ad * B[lane];
    const int base = b * SEQ_L + c * TCH;
    const float xs = x[base + lane];
    float h = 0.f;
    #pragma unroll
    for (int j = 0; j < TCH; ++j) {
        const float xj = __shfl(xs, j);
        h = fmaf(r, h, Bb * xj);
    }
    out[base + lane] = h;   // hloc[b][c][d=lane]
}

__global__ __launch_bounds__(256) void ssm_k2(const float* __restrict__ A,
                                              const float* __restrict__ logd,
                                              float* __restrict__ out)
{
    const int t = blockIdx.x * 256 + threadIdx.x;  // 4096 threads: (b,d)
    const int b = t >> 6;
    const int d = t & 63;
    const float delta = expf(logd[0]);
    const float rT = expf(64.f * delta * A[d]);    // r_d^T
    float h = 0.f;
    const int base = b * SEQ_L + d;
    for (int cg = 0; cg < NCH; cg += 16) {
        float tmp[16];
        #pragma unroll
        for (int k = 0; k < 16; ++k) tmp[k] = out[base + (cg + k) * TCH];
        #pragma unroll
        for (int k = 0; k < 16; ++k) {
            out[base + (cg + k) * TCH] = h;        // hin[b][cg+k][d]
            h = fmaf(rT, h, tmp[k]);
        }
    }
}

__global__ __launch_bounds__(256) void ssm_k3(const float* __restrict__ x,
                                              const float* __restrict__ ws,
                                              float* __restrict__ out)
{
    __shared__ float Mt[4096];
    __shared__ float Kp[127];
    for (int idx = threadIdx.x; idx < 4096; idx += 256) Mt[idx] = ws[idx];
    if (threadIdx.x < 127) Kp[threadIdx.x] = ws[4096 + threadIdx.x];
    __syncthreads();

    const int lane = threadIdx.x & 63;
    const int unit = blockIdx.x * 4 + (threadIdx.x >> 6);
    const int b = unit >> 7;
    const int c = unit & (NCH - 1);
    const int base = b * SEQ_L + c * TCH;
    const int i = lane;

    const float g  = out[base + lane];   // hin[b][c][d=lane] (read before overwrite)
    const float xs = x[base + lane];

    float acc0 = 0.f, acc1 = 0.f;
    #pragma unroll
    for (int d = 0; d < 64; d += 2) {
        acc0 = fmaf(Mt[d * 64 + i],       __shfl(g, d),     acc0);
        acc1 = fmaf(Mt[(d + 1) * 64 + i], __shfl(g, d + 1), acc1);
    }
    #pragma unroll
    for (int j = 0; j < 64; j += 2) {
        acc0 = fmaf(Kp[63 + i - j], __shfl(xs, j),     acc0);
        acc1 = fmaf(Kp[62 + i - j], __shfl(xs, j + 1), acc1);
    }
    out[base + i] = acc0 + acc1;
}

extern "C" void kernel_launch(void* const* d_in, const int* in_sizes, int n_in,
                              void* d_out, int out_size, void* d_ws, size_t ws_size,
                              hipStream_t stream) {
    const float* x    = (const float*)d_in[0];
    const float* A    = (const float*)d_in[1];
    const float* B    = (const float*)d_in[2];
    const float* C    = (const float*)d_in[3];
    const float* logd = (const float*)d_in[4];
    float* out = (float*)d_out;
    float* ws  = (float*)d_ws;   // needs 4223 floats (~17 KB)

    ssm_k1<<<(NB * NCH) / 4 + 1, 256, 0, stream>>>(x, A, B, C, logd, out, ws);
    ssm_k2<<<16, 256, 0, stream>>>(A, logd, out);
    ssm_k3<<<(NB * NCH) / 4, 256, 0, stream>>>(x, ws, out);
}

// Round 3
// 24.479 us; speedup vs baseline: 1.6560x; 1.6560x over previous
//
#include <hip/hip_runtime.h>

// Simple1DSSM: y = causal conv of x (64 x 8192) with SSM kernel K[m] = C diag(r^m) Bb.
// Chunk-parallel diagonal-state scan, 2 kernels:
//   K1: hloc[b][c][d] = Bb_d * sum_j r_d^{63-j} x[b,c*64+j]  -> d_ws
//       + one table block: Mt[d][i] = C_d r_d^{i+1}, Kp[63+m] = K[m]  -> d_ws
//   K2: g[b][c][d] = sum_{c'<c} (r_d^64)^{c-1-c'} hloc[b][c'][d]  (self-truncating:
//       r^64 <= e^{-64*delta}, loop exits when all lane weights < 1e-14; worst case exact)
//       y[b,c*64+i] = sum_d Mt[d][i] g_d + sum_{j<=i} K[i-j] x[b,c*64+j]

#define SEQ_L 8192
#define TCH   64
#define NCH   128
#define NB    64
#define HLOC  4352   // float offset of hloc in ws (tables take 0..4222)

__device__ __forceinline__ float rl(float v, int l) {
    return __int_as_float(__builtin_amdgcn_readlane(__float_as_int(v), l));
}

__global__ __launch_bounds__(256) void ssm_k1(const float* __restrict__ x,
                                              const float* __restrict__ A,
                                              const float* __restrict__ B,
                                              const float* __restrict__ C,
                                              const float* __restrict__ logd,
                                              float* __restrict__ ws)
{
    const float delta = expf(logd[0]);
    if (blockIdx.x == (NB * NCH) / 4) {
        // table block: 64 threads build Mt (4096 floats) and padded K (127 floats)
        if (threadIdx.x < 64) {
            const int i = threadIdx.x;
            float s = 0.f;
            for (int d = 0; d < 64; ++d) {
                const float Ad  = A[d];
                const float dAd = delta * Ad;
                const float rd  = expf(dAd);
                const float Bbd = (rd - 1.f) / Ad * B[d];
                const float wd  = C[d] * Bbd;
                const float p   = expf((float)i * dAd);   // r_d^i
                s = fmaf(wd, p, s);                       // K[i]
                ws[d * 64 + i] = C[d] * p * rd;           // Mt[d][i] = C_d r_d^{i+1}
            }
            ws[4096 + 63 + i] = s;                        // Kp[63+m] = K[m]
            if (i < 63) ws[4096 + i] = 0.f;               // Kp[m<0] = 0
        }
        return;
    }
    const int lane = threadIdx.x & 63;
    const int unit = blockIdx.x * 4 + (threadIdx.x >> 6);  // (b,c)
    const int b = unit >> 7;
    const int c = unit & (NCH - 1);
    const float dAd = delta * A[lane];
    const float r   = expf(dAd);
    const float Bb  = (r - 1.f) / A[lane] * B[lane];
    const int base = b * SEQ_L + c * TCH;
    const float xs = x[base + lane];   // raw x broadcast; Bb_d factored out of the chain
    // two independent 32-long chains; h_end = Bb * (r^32 * h0 + h1)
    float h0 = 0.f, h1 = 0.f;
    #pragma unroll
    for (int j = 0; j < 32; ++j)  h0 = fmaf(r, h0, rl(xs, j));
    #pragma unroll
    for (int j = 32; j < 64; ++j) h1 = fmaf(r, h1, rl(xs, j));
    const float r32 = expf(32.f * dAd);
    ws[HLOC + unit * 64 + lane] = Bb * fmaf(r32, h0, h1);
}

__global__ __launch_bounds__(256) void ssm_k2(const float* __restrict__ x,
                                              const float* __restrict__ A,
                                              const float* __restrict__ logd,
                                              const float* __restrict__ ws,
                                              float* __restrict__ out)
{
    __shared__ float Mt[4096];
    __shared__ float Kp[127];
    for (int idx = threadIdx.x; idx < 4096; idx += 256) Mt[idx] = ws[idx];
    if (threadIdx.x < 127) Kp[threadIdx.x] = ws[4096 + threadIdx.x];
    __syncthreads();

    const int lane = threadIdx.x & 63;
    const int unit = blockIdx.x * 4 + (threadIdx.x >> 6);
    const int b = unit >> 7;
    const int c = unit & (NCH - 1);
    const int base = b * SEQ_L + c * TCH;

    // --- incoming state via self-truncating chunk sum (lane = d) ---
    const float rT = expf(64.f * expf(logd[0]) * A[lane]);   // r_d^64
    float g = 0.f, w = 1.f;
    const float* hl = ws + HLOC + (b * NCH) * 64;
    for (int cp = c - 1; cp >= 0; --cp) {
        g = fmaf(w, hl[cp * 64 + lane], g);
        w *= rT;
        if (!__any(w > 1e-14f)) break;
    }

    // --- outputs (lane = i) ---
    const float xs = x[base + lane];
    float acc0 = 0.f, acc1 = 0.f;
    #pragma unroll
    for (int d = 0; d < 64; d += 2) {
        acc0 = fmaf(Mt[d * 64 + lane],       rl(g, d),     acc0);
        acc1 = fmaf(Mt[(d + 1) * 64 + lane], rl(g, d + 1), acc1);
    }
    #pragma unroll
    for (int j = 0; j < 64; j += 2) {
        acc0 = fmaf(Kp[63 + lane - j], rl(xs, j),     acc0);
        acc1 = fmaf(Kp[62 + lane - j], rl(xs, j + 1), acc1);
    }
    out[base + lane] = acc0 + acc1;
}

extern "C" void kernel_launch(void* const* d_in, const int* in_sizes, int n_in,
                              void* d_out, int out_size, void* d_ws, size_t ws_size,
                              hipStream_t stream) {
    const float* x    = (const float*)d_in[0];
    const float* A    = (const float*)d_in[1];
    const float* B    = (const float*)d_in[2];
    const float* C    = (const float*)d_in[3];
    const float* logd = (const float*)d_in[4];
    float* out = (float*)d_out;
    float* ws  = (float*)d_ws;   // uses 4352 + 64*128*64 floats (~2.1 MB)

    ssm_k1<<<(NB * NCH) / 4 + 1, 256, 0, stream>>>(x, A, B, C, logd, ws);
    ssm_k2<<<(NB * NCH) / 4, 256, 0, stream>>>(x, A, logd, ws, out);
}